// Round 1
// baseline (462.530 us; speedup 1.0000x reference)
//
#include <hip/hip_runtime.h>
#include <hip/hip_bf16.h>
#include <math.h>

// Problem constants (from reference)
#define NN 20000
#define NE 320000
#define TT 4
#define HH 128

// ---------------------------------------------------------------------------
// Kernel 1: per-(n,t) attention projections  proj_s/proj_d [N*T]
// one wave per (n,t) row of 128 features
__global__ void proj_kernel(const float* __restrict__ nf,
                            const float* __restrict__ a_src,
                            const float* __restrict__ a_dst,
                            float* __restrict__ ps, float* __restrict__ pd,
                            int total) {
    int wid  = (blockIdx.x * blockDim.x + threadIdx.x) >> 6;
    int lane = threadIdx.x & 63;
    if (wid >= total) return;
    const float* p = nf + (size_t)wid * HH;
    float v0 = p[lane], v1 = p[lane + 64];
    float s = v0 * a_src[lane] + v1 * a_src[lane + 64];
    float d = v0 * a_dst[lane] + v1 * a_dst[lane + 64];
    #pragma unroll
    for (int o = 32; o >= 1; o >>= 1) {
        s += __shfl_xor(s, o);
        d += __shfl_xor(d, o);
    }
    if (lane == 0) { ps[wid] = s; pd[wid] = d; }
}

// ---------------------------------------------------------------------------
// Kernel 2: degree histogram over dst
__global__ void hist_kernel(const int* __restrict__ dst, int* __restrict__ deg, int n) {
    int e = blockIdx.x * blockDim.x + threadIdx.x;
    if (e < n) atomicAdd(&deg[dst[e]], 1);
}

// ---------------------------------------------------------------------------
// Kernel 3: single-block exclusive scan -> offsets[0..N], offsets[0]=0
__global__ void scan_kernel(const int* __restrict__ deg, int* __restrict__ offsets, int n) {
    __shared__ int buf[1024];
    __shared__ int carry_s;
    int tid = threadIdx.x;
    if (tid == 0) carry_s = 0;
    __syncthreads();
    for (int base = 0; base < n; base += 1024) {
        int i = base + tid;
        int v = (i < n) ? deg[i] : 0;
        buf[tid] = v;
        __syncthreads();
        // Hillis-Steele inclusive scan
        for (int off = 1; off < 1024; off <<= 1) {
            int x = (tid >= off) ? buf[tid - off] : 0;
            __syncthreads();
            buf[tid] += x;
            __syncthreads();
        }
        int c = carry_s;  // all read old carry
        if (i < n) offsets[i + 1] = c + buf[tid];
        __syncthreads();
        if (tid == 0) carry_s = c + buf[1023];
        __syncthreads();
    }
    if (threadIdx.x == 0) offsets[0] = 0;
}

// ---------------------------------------------------------------------------
// Kernel 4: scatter edges into dst-sorted order (store src node id)
__global__ void scatter_kernel(const int* __restrict__ src, const int* __restrict__ dst,
                               const int* __restrict__ offsets, int* __restrict__ cursor,
                               int* __restrict__ ssrc, int n) {
    int e = blockIdx.x * blockDim.x + threadIdx.x;
    if (e < n) {
        int d = dst[e];
        int pos = atomicAdd(&cursor[d], 1);
        ssrc[offsets[d] + pos] = src[e];
    }
}

// ---------------------------------------------------------------------------
// Kernel 5: fused masked segment softmax + attention-weighted aggregation.
// block = 256 threads = 4 waves; block -> node d, wave -> timestep t.
// agg (= d_out) gets Sum_e alpha * nf[src,t,:]
__global__ void agg_kernel(const float* __restrict__ nf,
                           const int* __restrict__ events,
                           const float* __restrict__ ps,
                           const float* __restrict__ pd_arr,
                           const int* __restrict__ offsets,
                           const int* __restrict__ ssrc,
                           float* __restrict__ agg) {
    int t    = threadIdx.x >> 6;   // wave id = timestep
    int lane = threadIdx.x & 63;
    int d    = blockIdx.x;
    int off = offsets[d], end = offsets[d + 1];
    float pd = pd_arr[d * TT + t];

    // pass 1: segment max over active edges
    float m = -INFINITY;
    for (int i = off + lane; i < end; i += 64) {
        int s = ssrc[i];
        if (events[s * TT + t] == 1) {
            float x = ps[s * TT + t] + pd;
            x = (x > 0.f) ? x : 0.2f * x;   // leaky_relu 0.2
            m = fmaxf(m, x);
        }
    }
    #pragma unroll
    for (int o = 32; o >= 1; o >>= 1) m = fmaxf(m, __shfl_xor(m, o));

    float acc0 = 0.f, acc1 = 0.f;
    if (m > -INFINITY) {
        float den = 0.f;
        for (int base = off; base < end; base += 64) {
            int i = base + lane;
            float ex = 0.f;
            int s = 0;
            if (i < end) {
                s = ssrc[i];
                if (events[s * TT + t] == 1) {
                    float x = ps[s * TT + t] + pd;
                    x = (x > 0.f) ? x : 0.2f * x;
                    ex = __expf(x - m);
                }
            }
            den += ex;
            int cnt = min(64, end - base);
            for (int j = 0; j < cnt; ++j) {
                float exj = __shfl(ex, j);
                if (exj > 0.f) {
                    int sj = __shfl(s, j);
                    const float* p = nf + ((size_t)sj * TT + t) * HH;
                    acc0 += exj * p[lane];
                    acc1 += exj * p[lane + 64];
                }
            }
        }
        #pragma unroll
        for (int o = 32; o >= 1; o >>= 1) den += __shfl_xor(den, o);
        float scale = 1.f / fmaxf(den, 1e-9f);
        acc0 *= scale;
        acc1 *= scale;
    }
    float* out = agg + ((size_t)d * TT + t) * HH;
    out[lane]      = acc0;
    out[lane + 64] = acc1;
}

// ---------------------------------------------------------------------------
// Kernel 6: out = relu(concat([nf, agg]) @ W + b), in-place over agg (d_out).
// block = 256 threads handles 8 rows; thread -> (row r = tid>>5, 4 cols j = (tid&31)*4).
__global__ void out_kernel(const float* __restrict__ nf,
                           const float* __restrict__ W,
                           const float* __restrict__ b,
                           float* __restrict__ out /* also agg input */) {
    __shared__ float xs[8][256];
    int tid = threadIdx.x;
    size_t row0 = (size_t)blockIdx.x * 8;

    // stage 8 rows of concat([nf_row, agg_row]) into LDS
    for (int idx = tid; idx < 8 * 256; idx += 256) {
        int r = idx >> 8;
        int k = idx & 255;
        size_t row = row0 + r;
        xs[r][k] = (k < 128) ? nf[row * HH + k] : out[row * HH + (k - 128)];
    }
    __syncthreads();

    int jg = tid & 31;        // 4-col group
    int r  = tid >> 5;        // row within block (0..7)
    float4 bv = *reinterpret_cast<const float4*>(&b[jg * 4]);
    float a0 = bv.x, a1 = bv.y, a2 = bv.z, a3 = bv.w;
    #pragma unroll 4
    for (int k = 0; k < 256; ++k) {
        float4 w = *reinterpret_cast<const float4*>(&W[(size_t)k * HH + jg * 4]);
        float x = xs[r][k];
        a0 += x * w.x; a1 += x * w.y; a2 += x * w.z; a3 += x * w.w;
    }
    float4 res;
    res.x = fmaxf(a0, 0.f); res.y = fmaxf(a1, 0.f);
    res.z = fmaxf(a2, 0.f); res.w = fmaxf(a3, 0.f);
    *reinterpret_cast<float4*>(&out[(row0 + r) * HH + jg * 4]) = res;
}

// ---------------------------------------------------------------------------
extern "C" void kernel_launch(void* const* d_in, const int* in_sizes, int n_in,
                              void* d_out, int out_size, void* d_ws, size_t ws_size,
                              hipStream_t stream) {
    const float* nf      = (const float*)d_in[0];
    const int*   events  = (const int*)  d_in[1];
    const int*   src     = (const int*)  d_in[2];
    const int*   dst     = (const int*)  d_in[3];
    const float* a_src   = (const float*)d_in[4];
    const float* a_dst   = (const float*)d_in[5];
    const float* W       = (const float*)d_in[6];
    const float* b       = (const float*)d_in[7];
    float* out = (float*)d_out;

    // workspace layout (all 256B aligned)
    char* ws = (char*)d_ws;
    float* proj_s  = (float*)(ws);                    // N*T floats = 1.28 MB
    float* proj_d  = (float*)(ws + 1310720);          // N*T floats
    int*   offsets = (int*)  (ws + 2621440);          // N+1 ints
    int*   deg     = (int*)  (ws + 2703360);          // N ints (reused as cursor)
    int*   ssrc    = (int*)  (ws + 2785280);          // E ints
    // total ~4.07 MB

    const int total_nt = NN * TT;   // 80000

    // 1. projections
    proj_kernel<<<total_nt / 4, 256, 0, stream>>>(nf, a_src, a_dst, proj_s, proj_d, total_nt);

    // 2. histogram
    hipMemsetAsync(deg, 0, NN * sizeof(int), stream);
    hist_kernel<<<(NE + 255) / 256, 256, 0, stream>>>(dst, deg, NE);

    // 3. scan
    scan_kernel<<<1, 1024, 0, stream>>>(deg, offsets, NN);

    // 4. scatter (deg reused as cursor)
    hipMemsetAsync(deg, 0, NN * sizeof(int), stream);
    scatter_kernel<<<(NE + 255) / 256, 256, 0, stream>>>(src, dst, offsets, deg, ssrc, NE);

    // 5. fused softmax + aggregation -> d_out holds agg
    agg_kernel<<<NN, 256, 0, stream>>>(nf, events, proj_s, proj_d, offsets, ssrc, out);

    // 6. node update matmul + relu, in place
    out_kernel<<<total_nt / 8, 256, 0, stream>>>(nf, W, b, out);
}

// Round 2
// 195.593 us; speedup vs baseline: 2.3648x; 2.3648x over previous
//
#include <hip/hip_runtime.h>
#include <hip/hip_bf16.h>
#include <math.h>

// Problem constants (from reference)
#define NN 20000
#define NE 320000
#define TT 4
#define HH 128

typedef __attribute__((ext_vector_type(8))) short short8v;  // 8 bf16 = 4 VGPRs
typedef __attribute__((ext_vector_type(4))) float f32x4;

static __device__ __forceinline__ unsigned short f2bf(float v) {
    union { float f; unsigned u; } x; x.f = v;
    unsigned r = x.u + 0x7fff + ((x.u >> 16) & 1);   // RNE
    return (unsigned short)(r >> 16);
}

// ---------------------------------------------------------------------------
// Kernel 1: per-(n,t) attention projections  proj_s/proj_d [N*T]
__global__ void proj_kernel(const float* __restrict__ nf,
                            const float* __restrict__ a_src,
                            const float* __restrict__ a_dst,
                            float* __restrict__ ps, float* __restrict__ pd,
                            int total) {
    int wid  = (blockIdx.x * blockDim.x + threadIdx.x) >> 6;
    int lane = threadIdx.x & 63;
    if (wid >= total) return;
    const float* p = nf + (size_t)wid * HH;
    float v0 = p[lane], v1 = p[lane + 64];
    float s = v0 * a_src[lane] + v1 * a_src[lane + 64];
    float d = v0 * a_dst[lane] + v1 * a_dst[lane + 64];
    #pragma unroll
    for (int o = 32; o >= 1; o >>= 1) {
        s += __shfl_xor(s, o);
        d += __shfl_xor(d, o);
    }
    if (lane == 0) { ps[wid] = s; pd[wid] = d; }
}

// ---------------------------------------------------------------------------
// Kernel 2: degree histogram over dst
__global__ void hist_kernel(const int* __restrict__ dst, int* __restrict__ deg, int n) {
    int e = blockIdx.x * blockDim.x + threadIdx.x;
    if (e < n) atomicAdd(&deg[dst[e]], 1);
}

// ---------------------------------------------------------------------------
// Kernel 3: single-block exclusive scan -> offsets[0..N], offsets[0]=0
__global__ void scan_kernel(const int* __restrict__ deg, int* __restrict__ offsets, int n) {
    __shared__ int buf[1024];
    __shared__ int carry_s;
    int tid = threadIdx.x;
    if (tid == 0) carry_s = 0;
    __syncthreads();
    for (int base = 0; base < n; base += 1024) {
        int i = base + tid;
        int v = (i < n) ? deg[i] : 0;
        buf[tid] = v;
        __syncthreads();
        for (int off = 1; off < 1024; off <<= 1) {
            int x = (tid >= off) ? buf[tid - off] : 0;
            __syncthreads();
            buf[tid] += x;
            __syncthreads();
        }
        int c = carry_s;
        if (i < n) offsets[i + 1] = c + buf[tid];
        __syncthreads();
        if (tid == 0) carry_s = c + buf[1023];
        __syncthreads();
    }
    if (threadIdx.x == 0) offsets[0] = 0;
}

// ---------------------------------------------------------------------------
// Kernel 4: scatter edges into dst-sorted order (store src node id)
__global__ void scatter_kernel(const int* __restrict__ src, const int* __restrict__ dst,
                               const int* __restrict__ offsets, int* __restrict__ cursor,
                               int* __restrict__ ssrc, int n) {
    int e = blockIdx.x * blockDim.x + threadIdx.x;
    if (e < n) {
        int d = dst[e];
        int pos = atomicAdd(&cursor[d], 1);
        ssrc[offsets[d] + pos] = src[e];
    }
}

// ---------------------------------------------------------------------------
// Kernel 5: fused masked segment softmax + attention-weighted aggregation.
__global__ void agg_kernel(const float* __restrict__ nf,
                           const int* __restrict__ events,
                           const float* __restrict__ ps,
                           const float* __restrict__ pd_arr,
                           const int* __restrict__ offsets,
                           const int* __restrict__ ssrc,
                           float* __restrict__ agg) {
    int t    = threadIdx.x >> 6;   // wave id = timestep
    int lane = threadIdx.x & 63;
    int d    = blockIdx.x;
    int off = offsets[d], end = offsets[d + 1];
    float pd = pd_arr[d * TT + t];

    float m = -INFINITY;
    for (int i = off + lane; i < end; i += 64) {
        int s = ssrc[i];
        if (events[s * TT + t] == 1) {
            float x = ps[s * TT + t] + pd;
            x = (x > 0.f) ? x : 0.2f * x;   // leaky_relu 0.2
            m = fmaxf(m, x);
        }
    }
    #pragma unroll
    for (int o = 32; o >= 1; o >>= 1) m = fmaxf(m, __shfl_xor(m, o));

    float acc0 = 0.f, acc1 = 0.f;
    if (m > -INFINITY) {
        float den = 0.f;
        for (int base = off; base < end; base += 64) {
            int i = base + lane;
            float ex = 0.f;
            int s = 0;
            if (i < end) {
                s = ssrc[i];
                if (events[s * TT + t] == 1) {
                    float x = ps[s * TT + t] + pd;
                    x = (x > 0.f) ? x : 0.2f * x;
                    ex = __expf(x - m);
                }
            }
            den += ex;
            int cnt = min(64, end - base);
            for (int j = 0; j < cnt; ++j) {
                float exj = __shfl(ex, j);
                if (exj > 0.f) {
                    int sj = __shfl(s, j);
                    const float* p = nf + ((size_t)sj * TT + t) * HH;
                    acc0 += exj * p[lane];
                    acc1 += exj * p[lane + 64];
                }
            }
        }
        #pragma unroll
        for (int o = 32; o >= 1; o >>= 1) den += __shfl_xor(den, o);
        float scale = 1.f / fmaxf(den, 1e-9f);
        acc0 *= scale;
        acc1 *= scale;
    }
    float* out = agg + ((size_t)d * TT + t) * HH;
    out[lane]      = acc0;
    out[lane + 64] = acc1;
}

// ---------------------------------------------------------------------------
// Kernel 6a: pack W (fp32 [256][128]) into bf16 MFMA B-fragment order.
// frag f = (kstep*8 + ntile)*64 + lane holds W[kstep*32+(lane>>4)*8+j][ntile*16+(lane&15)], j=0..7
__global__ void wpack_kernel(const float* __restrict__ W, uint4* __restrict__ wp) {
    int f = blockIdx.x * blockDim.x + threadIdx.x;
    if (f >= 8 * 8 * 64) return;
    int lane  = f & 63;
    int tile  = f >> 6;
    int kstep = tile >> 3, ntile = tile & 7;
    int k0 = kstep * 32 + (lane >> 4) * 8;
    int n  = ntile * 16 + (lane & 15);
    unsigned short h[8];
    #pragma unroll
    for (int j = 0; j < 8; ++j)
        h[j] = f2bf(W[(size_t)(k0 + j) * HH + n]);
    uint4 q;
    q.x = h[0] | ((unsigned)h[1] << 16);
    q.y = h[2] | ((unsigned)h[3] << 16);
    q.z = h[4] | ((unsigned)h[5] << 16);
    q.w = h[6] | ((unsigned)h[7] << 16);
    wp[f] = q;
}

// ---------------------------------------------------------------------------
// Kernel 6b: out = relu(concat([nf, agg]) @ W + b) via bf16 MFMA, in-place over agg.
// block = 256 thr = 4 waves; 64 rows x 128 cols per block, K = 256.
// LDS x-tile [64 rows][32 x 16B chunks], XOR-swizzled by (row&7) in chunk units.
__global__ __launch_bounds__(256) void out_mfma_kernel(
        const float* __restrict__ nf, const uint4* __restrict__ wp,
        const float* __restrict__ b, float* __restrict__ out) {
    __shared__ uint4 xs[2048];   // 32 KB
    int tid = threadIdx.x;
    size_t row0 = (size_t)blockIdx.x * 64;

    // stage: convert 64 rows of concat([nf,agg]) to bf16 chunks
    #pragma unroll
    for (int i = 0; i < 8; ++i) {
        int c = i * 256 + tid;
        int row = c >> 5, kc = c & 31;
        const float* srcp = (kc < 16) ? (nf  + (row0 + row) * HH + kc * 8)
                                      : (out + (row0 + row) * HH + (kc - 16) * 8);
        float4 v0 = *reinterpret_cast<const float4*>(srcp);
        float4 v1 = *reinterpret_cast<const float4*>(srcp + 4);
        uint4 q;
        q.x = f2bf(v0.x) | ((unsigned)f2bf(v0.y) << 16);
        q.y = f2bf(v0.z) | ((unsigned)f2bf(v0.w) << 16);
        q.z = f2bf(v1.x) | ((unsigned)f2bf(v1.y) << 16);
        q.w = f2bf(v1.z) | ((unsigned)f2bf(v1.w) << 16);
        xs[(row * 32 + kc) ^ (row & 7)] = q;
    }
    __syncthreads();

    int w = tid >> 6, l = tid & 63;
    f32x4 acc[8];
    #pragma unroll
    for (int nt = 0; nt < 8; ++nt) acc[nt] = (f32x4){0.f, 0.f, 0.f, 0.f};

    int arow = w * 16 + (l & 15);
    const uint4* wplane = wp + l;
    #pragma unroll
    for (int ks = 0; ks < 8; ++ks) {
        int kc = ks * 4 + (l >> 4);
        uint4 av = xs[(arow * 32 + kc) ^ (arow & 7)];
        short8v af = __builtin_bit_cast(short8v, av);
        #pragma unroll
        for (int nt = 0; nt < 8; ++nt) {
            uint4 bv = wplane[(ks * 8 + nt) * 64];
            short8v bf = __builtin_bit_cast(short8v, bv);
            acc[nt] = __builtin_amdgcn_mfma_f32_16x16x32_bf16(af, bf, acc[nt], 0, 0, 0);
        }
    }

    // epilogue: C/D layout col=lane&15, row=(lane>>4)*4+reg
    int col = l & 15, rquad = (l >> 4) * 4;
    #pragma unroll
    for (int nt = 0; nt < 8; ++nt) {
        float bias = b[nt * 16 + col];
        #pragma unroll
        for (int r = 0; r < 4; ++r) {
            float v = acc[nt][r] + bias;
            out[(row0 + w * 16 + rquad + r) * HH + nt * 16 + col] = fmaxf(v, 0.f);
        }
    }
}

// ---------------------------------------------------------------------------
extern "C" void kernel_launch(void* const* d_in, const int* in_sizes, int n_in,
                              void* d_out, int out_size, void* d_ws, size_t ws_size,
                              hipStream_t stream) {
    const float* nf      = (const float*)d_in[0];
    const int*   events  = (const int*)  d_in[1];
    const int*   src     = (const int*)  d_in[2];
    const int*   dst     = (const int*)  d_in[3];
    const float* a_src   = (const float*)d_in[4];
    const float* a_dst   = (const float*)d_in[5];
    const float* W       = (const float*)d_in[6];
    const float* b       = (const float*)d_in[7];
    float* out = (float*)d_out;

    // workspace layout (same footprint as round 1: ~4.07 MB)
    char* ws = (char*)d_ws;
    float* proj_s  = (float*)(ws);                    // N*T floats; dead after agg
    float* proj_d  = (float*)(ws + 1310720);          // N*T floats
    int*   offsets = (int*)  (ws + 2621440);          // N+1 ints
    int*   deg     = (int*)  (ws + 2703360);          // N ints (reused as cursor)
    int*   ssrc    = (int*)  (ws + 2785280);          // E ints
    uint4* wpack   = (uint4*)(ws);                    // 64 KB, aliases dead proj_s

    const int total_nt = NN * TT;   // 80000

    proj_kernel<<<total_nt / 4, 256, 0, stream>>>(nf, a_src, a_dst, proj_s, proj_d, total_nt);

    hipMemsetAsync(deg, 0, NN * sizeof(int), stream);
    hist_kernel<<<(NE + 255) / 256, 256, 0, stream>>>(dst, deg, NE);

    scan_kernel<<<1, 1024, 0, stream>>>(deg, offsets, NN);

    hipMemsetAsync(deg, 0, NN * sizeof(int), stream);
    scatter_kernel<<<(NE + 255) / 256, 256, 0, stream>>>(src, dst, offsets, deg, ssrc, NE);

    agg_kernel<<<NN, 256, 0, stream>>>(nf, events, proj_s, proj_d, offsets, ssrc, out);

    // proj_s dead now -> pack W into its slot, then MFMA node update in-place
    wpack_kernel<<<16, 256, 0, stream>>>(W, wpack);
    out_mfma_kernel<<<total_nt / 8 / 8, 256, 0, stream>>>(nf, wpack, b, out);
}

// Round 3
// 168.789 us; speedup vs baseline: 2.7403x; 1.1588x over previous
//
#include <hip/hip_runtime.h>
#include <hip/hip_bf16.h>
#include <math.h>

// Problem constants (from reference)
#define NN 20000
#define NE 320000
#define TT 4
#define HH 128

typedef __attribute__((ext_vector_type(8))) short short8v;  // 8 bf16 = 4 VGPRs
typedef __attribute__((ext_vector_type(4))) float f32x4;

static __device__ __forceinline__ unsigned short f2bf(float v) {
    union { float f; unsigned u; } x; x.f = v;
    unsigned r = x.u + 0x7fff + ((x.u >> 16) & 1);   // RNE
    return (unsigned short)(r >> 16);
}

// ---------------------------------------------------------------------------
// Kernel 1: per-(n,t) projections. Writes psm = event ? <nf,a_src> : -1e30
// (pre-masked so agg does ONE gather per edge), pdv = <nf,a_dst>.
__global__ void proj_kernel(const float* __restrict__ nf,
                            const int* __restrict__ events,
                            const float* __restrict__ a_src,
                            const float* __restrict__ a_dst,
                            float* __restrict__ psm, float* __restrict__ pdv,
                            int total) {
    int wid  = (blockIdx.x * blockDim.x + threadIdx.x) >> 6;
    int lane = threadIdx.x & 63;
    if (wid >= total) return;
    float2 v  = ((const float2*)nf)[(size_t)wid * 64 + lane];
    float2 as = ((const float2*)a_src)[lane];
    float2 ad = ((const float2*)a_dst)[lane];
    float s  = v.x * as.x + v.y * as.y;
    float dd = v.x * ad.x + v.y * ad.y;
    #pragma unroll
    for (int o = 32; o >= 1; o >>= 1) {
        s  += __shfl_xor(s, o);
        dd += __shfl_xor(dd, o);
    }
    if (lane == 0) {
        psm[wid] = (events[wid] == 1) ? s : -1e30f;
        pdv[wid] = dd;
    }
}

// ---------------------------------------------------------------------------
// Kernel 2: degree histogram over dst
__global__ void hist_kernel(const int* __restrict__ dst, int* __restrict__ deg, int n) {
    int e = blockIdx.x * blockDim.x + threadIdx.x;
    if (e < n) atomicAdd(&deg[dst[e]], 1);
}

// ---------------------------------------------------------------------------
// Kernel 3: single-block scan, 20 elems/thread + wave-shuffle (3 barriers).
// Writes offsets[0..N] and cursor[0..N] (= offsets copy for scatter).
#define SCAN_PER 20
__global__ __launch_bounds__(1024) void scan_kernel(
        const int* __restrict__ deg, int* __restrict__ offsets,
        int* __restrict__ cursor, int n) {
    __shared__ int wsum[16];
    __shared__ int wpre[16];
    int tid  = threadIdx.x;
    int lane = tid & 63, wid = tid >> 6;
    int base = tid * SCAN_PER;
    int loc[SCAN_PER];
    int s = 0;
    #pragma unroll
    for (int k = 0; k < SCAN_PER; ++k) {
        int i = base + k;
        int v = (i < n) ? deg[i] : 0;
        loc[k] = v; s += v;
    }
    int inc = s;
    #pragma unroll
    for (int o = 1; o < 64; o <<= 1) {
        int x = __shfl_up(inc, o);
        if (lane >= o) inc += x;
    }
    if (lane == 63) wsum[wid] = inc;
    __syncthreads();
    if (wid == 0 && lane < 16) {
        int v = wsum[lane];
        int w = v;
        #pragma unroll
        for (int o = 1; o < 16; o <<= 1) {
            int x = __shfl_up(w, o);
            if (lane >= o) w += x;
        }
        wpre[lane] = w - v;   // exclusive
    }
    __syncthreads();
    int run = wpre[wid] + (inc - s);   // exclusive prefix for this thread
    #pragma unroll
    for (int k = 0; k < SCAN_PER; ++k) {
        int i = base + k;
        if (i < n) {
            run += loc[k];
            offsets[i + 1] = run;
            cursor[i + 1]  = run;
        }
    }
    if (tid == 0) { offsets[0] = 0; cursor[0] = 0; }
}

// ---------------------------------------------------------------------------
// Kernel 4: scatter edges into dst-sorted order (cursor pre-seeded = offsets)
__global__ void scatter_kernel(const int* __restrict__ src, const int* __restrict__ dst,
                               int* __restrict__ cursor, int* __restrict__ ssrc, int n) {
    int e = blockIdx.x * blockDim.x + threadIdx.x;
    if (e < n) {
        int pos = atomicAdd(&cursor[dst[e]], 1);
        ssrc[pos] = src[e];
    }
}

// ---------------------------------------------------------------------------
// Kernel 5: fused masked segment softmax + aggregation, single pass (no max),
// ballot-compaction of active edges, 4-deep ILP gather loop.
// block = 256 thr = 4 waves; block -> node d, wave -> timestep t.
__global__ __launch_bounds__(256) void agg_kernel(
        const float* __restrict__ nf,
        const float* __restrict__ psm,
        const float* __restrict__ pdv,
        const int* __restrict__ offsets,
        const int* __restrict__ ssrc,
        float* __restrict__ agg) {
    __shared__ int2 led[TT][64];
    int t    = threadIdx.x >> 6;
    int lane = threadIdx.x & 63;
    int d    = blockIdx.x;
    int off = offsets[d], end = offsets[d + 1];
    float pd = pdv[d * TT + t];
    const float2* nf2 = (const float2*)nf;
    size_t tl = (size_t)t * 64 + lane;

    float2 acc = {0.f, 0.f};
    float den = 0.f;
    for (int base = off; base < end; base += 64) {
        int i = base + lane;
        float ex = 0.f; int s = 0;
        if (i < end) {
            s = ssrc[i];
            float p = psm[s * TT + t];
            if (p > -1e29f) {
                float x = p + pd;
                x = (x > 0.f) ? x : 0.2f * x;   // leaky_relu 0.2
                ex = __expf(x);
            }
        }
        den += ex;
        unsigned long long mask = __ballot(ex > 0.f);
        int nact = __popcll(mask);
        if (ex > 0.f) {
            int pos = __popcll(mask & ((1ull << lane) - 1ull));
            led[t][pos] = make_int2(s, __float_as_int(ex));
        }
        int j = 0;
        for (; j + 4 <= nact; j += 4) {
            int2 a0 = led[t][j], a1 = led[t][j + 1], a2 = led[t][j + 2], a3 = led[t][j + 3];
            float2 r0 = nf2[(size_t)a0.x * 256 + tl];
            float2 r1 = nf2[(size_t)a1.x * 256 + tl];
            float2 r2 = nf2[(size_t)a2.x * 256 + tl];
            float2 r3 = nf2[(size_t)a3.x * 256 + tl];
            float e0 = __int_as_float(a0.y), e1 = __int_as_float(a1.y);
            float e2 = __int_as_float(a2.y), e3 = __int_as_float(a3.y);
            acc.x += e0 * r0.x; acc.y += e0 * r0.y;
            acc.x += e1 * r1.x; acc.y += e1 * r1.y;
            acc.x += e2 * r2.x; acc.y += e2 * r2.y;
            acc.x += e3 * r3.x; acc.y += e3 * r3.y;
        }
        for (; j < nact; ++j) {
            int2 a = led[t][j];
            float2 r = nf2[(size_t)a.x * 256 + tl];
            float e = __int_as_float(a.y);
            acc.x += e * r.x; acc.y += e * r.y;
        }
    }
    #pragma unroll
    for (int o = 32; o >= 1; o >>= 1) den += __shfl_xor(den, o);
    float scale = (den > 0.f) ? (1.f / den) : 0.f;  // den >= exp(-90) when any active
    float2 res; res.x = acc.x * scale; res.y = acc.y * scale;
    ((float2*)agg)[(size_t)d * 256 + tl] = res;
}

// ---------------------------------------------------------------------------
// Kernel 6a: pack W (fp32 [256][128]) into bf16 MFMA B-fragment order.
__global__ void wpack_kernel(const float* __restrict__ W, uint4* __restrict__ wp) {
    int f = blockIdx.x * blockDim.x + threadIdx.x;
    if (f >= 8 * 8 * 64) return;
    int lane  = f & 63;
    int tile  = f >> 6;
    int kstep = tile >> 3, ntile = tile & 7;
    int k0 = kstep * 32 + (lane >> 4) * 8;
    int n  = ntile * 16 + (lane & 15);
    unsigned short h[8];
    #pragma unroll
    for (int j = 0; j < 8; ++j)
        h[j] = f2bf(W[(size_t)(k0 + j) * HH + n]);
    uint4 q;
    q.x = h[0] | ((unsigned)h[1] << 16);
    q.y = h[2] | ((unsigned)h[3] << 16);
    q.z = h[4] | ((unsigned)h[5] << 16);
    q.w = h[6] | ((unsigned)h[7] << 16);
    wp[f] = q;
}

// ---------------------------------------------------------------------------
// Kernel 6b: out = relu(concat([nf, agg]) @ W + b) via bf16 MFMA, in-place.
__global__ __launch_bounds__(256) void out_mfma_kernel(
        const float* __restrict__ nf, const uint4* __restrict__ wp,
        const float* __restrict__ b, float* __restrict__ out) {
    __shared__ uint4 xs[2048];   // 32 KB
    int tid = threadIdx.x;
    size_t row0 = (size_t)blockIdx.x * 64;

    #pragma unroll
    for (int i = 0; i < 8; ++i) {
        int c = i * 256 + tid;
        int row = c >> 5, kc = c & 31;
        const float* srcp = (kc < 16) ? (nf  + (row0 + row) * HH + kc * 8)
                                      : (out + (row0 + row) * HH + (kc - 16) * 8);
        float4 v0 = *reinterpret_cast<const float4*>(srcp);
        float4 v1 = *reinterpret_cast<const float4*>(srcp + 4);
        uint4 q;
        q.x = f2bf(v0.x) | ((unsigned)f2bf(v0.y) << 16);
        q.y = f2bf(v0.z) | ((unsigned)f2bf(v0.w) << 16);
        q.z = f2bf(v1.x) | ((unsigned)f2bf(v1.y) << 16);
        q.w = f2bf(v1.z) | ((unsigned)f2bf(v1.w) << 16);
        xs[(row * 32 + kc) ^ (row & 7)] = q;
    }
    __syncthreads();

    int w = tid >> 6, l = tid & 63;
    f32x4 acc[8];
    #pragma unroll
    for (int nt = 0; nt < 8; ++nt) acc[nt] = (f32x4){0.f, 0.f, 0.f, 0.f};

    int arow = w * 16 + (l & 15);
    const uint4* wplane = wp + l;
    #pragma unroll
    for (int ks = 0; ks < 8; ++ks) {
        int kc = ks * 4 + (l >> 4);
        uint4 av = xs[(arow * 32 + kc) ^ (arow & 7)];
        short8v af = __builtin_bit_cast(short8v, av);
        #pragma unroll
        for (int nt = 0; nt < 8; ++nt) {
            uint4 bv = wplane[(ks * 8 + nt) * 64];
            short8v bf = __builtin_bit_cast(short8v, bv);
            acc[nt] = __builtin_amdgcn_mfma_f32_16x16x32_bf16(af, bf, acc[nt], 0, 0, 0);
        }
    }

    int col = l & 15, rquad = (l >> 4) * 4;
    #pragma unroll
    for (int nt = 0; nt < 8; ++nt) {
        float bias = b[nt * 16 + col];
        #pragma unroll
        for (int r = 0; r < 4; ++r) {
            float v = acc[nt][r] + bias;
            out[(row0 + w * 16 + rquad + r) * HH + nt * 16 + col] = fmaxf(v, 0.f);
        }
    }
}

// ---------------------------------------------------------------------------
extern "C" void kernel_launch(void* const* d_in, const int* in_sizes, int n_in,
                              void* d_out, int out_size, void* d_ws, size_t ws_size,
                              hipStream_t stream) {
    const float* nf      = (const float*)d_in[0];
    const int*   events  = (const int*)  d_in[1];
    const int*   src     = (const int*)  d_in[2];
    const int*   dst     = (const int*)  d_in[3];
    const float* a_src   = (const float*)d_in[4];
    const float* a_dst   = (const float*)d_in[5];
    const float* W       = (const float*)d_in[6];
    const float* b       = (const float*)d_in[7];
    float* out = (float*)d_out;

    // workspace layout (~4.15 MB)
    char* ws = (char*)d_ws;
    float* psm     = (float*)(ws);                    // N*T floats; dead after agg
    float* pdv     = (float*)(ws + 1310720);          // N*T floats
    int*   offsets = (int*)  (ws + 2621440);          // N+1 ints
    int*   deg     = (int*)  (ws + 2703360);          // N ints
    int*   cursor  = (int*)  (ws + 2785280);          // N+1 ints
    int*   ssrc    = (int*)  (ws + 2867200);          // E ints
    uint4* wpack   = (uint4*)(ws);                    // 64 KB, aliases dead psm

    const int total_nt = NN * TT;   // 80000

    hipMemsetAsync(deg, 0, NN * sizeof(int), stream);
    proj_kernel<<<total_nt / 4, 256, 0, stream>>>(nf, events, a_src, a_dst, psm, pdv, total_nt);
    hist_kernel<<<(NE + 255) / 256, 256, 0, stream>>>(dst, deg, NE);
    scan_kernel<<<1, 1024, 0, stream>>>(deg, offsets, cursor, NN);
    scatter_kernel<<<(NE + 255) / 256, 256, 0, stream>>>(src, dst, cursor, ssrc, NE);
    agg_kernel<<<NN, 256, 0, stream>>>(nf, psm, pdv, offsets, ssrc, out);

    // psm dead now -> pack W into its slot, then MFMA node update in-place
    wpack_kernel<<<16, 256, 0, stream>>>(W, wpack);
    out_mfma_kernel<<<total_nt / 8 / 8, 256, 0, stream>>>(nf, wpack, b, out);
}

// Round 4
// 142.179 us; speedup vs baseline: 3.2531x; 1.1872x over previous
//
#include <hip/hip_runtime.h>
#include <hip/hip_bf16.h>
#include <math.h>

// Problem constants (from reference)
#define NN 20000
#define NE 320000
#define TT 4
#define HH 128

typedef __attribute__((ext_vector_type(8))) short short8v;  // 8 bf16 = 4 VGPRs
typedef __attribute__((ext_vector_type(4))) float f32x4;

static __device__ __forceinline__ unsigned short f2bf(float v) {
    union { float f; unsigned u; } x; x.f = v;
    unsigned r = x.u + 0x7fff + ((x.u >> 16) & 1);   // RNE
    return (unsigned short)(r >> 16);
}
static __device__ __forceinline__ unsigned pack2bf(float a, float b) {
    return (unsigned)f2bf(a) | ((unsigned)f2bf(b) << 16);
}
static __device__ __forceinline__ float bf_lo(unsigned v) { return __uint_as_float(v << 16); }
static __device__ __forceinline__ float bf_hi(unsigned v) { return __uint_as_float(v & 0xffff0000u); }

// ===========================================================================
// Shared kernels (both tiers)
// ===========================================================================

// single-block scan, 20 elems/thread + wave-shuffle (3 barriers).
#define SCAN_PER 20
__global__ __launch_bounds__(1024) void scan_kernel(
        const int* __restrict__ deg, int* __restrict__ offsets,
        int* __restrict__ cursor, int n) {
    __shared__ int wsum[16];
    __shared__ int wpre[16];
    int tid  = threadIdx.x;
    int lane = tid & 63, wid = tid >> 6;
    int base = tid * SCAN_PER;
    int loc[SCAN_PER];
    int s = 0;
    #pragma unroll
    for (int k = 0; k < SCAN_PER; ++k) {
        int i = base + k;
        int v = (i < n) ? deg[i] : 0;
        loc[k] = v; s += v;
    }
    int inc = s;
    #pragma unroll
    for (int o = 1; o < 64; o <<= 1) {
        int x = __shfl_up(inc, o);
        if (lane >= o) inc += x;
    }
    if (lane == 63) wsum[wid] = inc;
    __syncthreads();
    if (wid == 0 && lane < 16) {
        int v = wsum[lane];
        int w = v;
        #pragma unroll
        for (int o = 1; o < 16; o <<= 1) {
            int x = __shfl_up(w, o);
            if (lane >= o) w += x;
        }
        wpre[lane] = w - v;   // exclusive
    }
    __syncthreads();
    int run = wpre[wid] + (inc - s);
    #pragma unroll
    for (int k = 0; k < SCAN_PER; ++k) {
        int i = base + k;
        if (i < n) {
            run += loc[k];
            offsets[i + 1] = run;
            cursor[i + 1]  = run;
        }
    }
    if (tid == 0) { offsets[0] = 0; cursor[0] = 0; }
}

__global__ void scatter_kernel(const int* __restrict__ src, const int* __restrict__ dst,
                               int* __restrict__ cursor, int* __restrict__ ssrc, int n) {
    int e = blockIdx.x * blockDim.x + threadIdx.x;
    if (e < n) {
        int pos = atomicAdd(&cursor[dst[e]], 1);
        ssrc[pos] = src[e];
    }
}

// ===========================================================================
// Tier A (big workspace): bf16 gather table
// ===========================================================================

// fused: blocks [0,20000) proj (+bf16 nf copy), [20000,21250) hist, [21250,21266) wpack
__global__ __launch_bounds__(256) void fusedA_kernel(
        const float* __restrict__ nf, const int* __restrict__ events,
        const float* __restrict__ a_src, const float* __restrict__ a_dst,
        const int* __restrict__ dst, const float* __restrict__ W,
        float* __restrict__ psm, float* __restrict__ pdv,
        unsigned* __restrict__ nfb, int* __restrict__ deg,
        uint4* __restrict__ wp) {
    int blk = blockIdx.x, tid = threadIdx.x;
    if (blk < 20000) {
        int wid  = blk * 4 + (tid >> 6);
        int lane = tid & 63;
        float2 v  = ((const float2*)nf)[(size_t)wid * 64 + lane];
        nfb[(size_t)wid * 64 + lane] = pack2bf(v.x, v.y);
        float2 as = ((const float2*)a_src)[lane];
        float2 ad = ((const float2*)a_dst)[lane];
        float s  = v.x * as.x + v.y * as.y;
        float dd = v.x * ad.x + v.y * ad.y;
        #pragma unroll
        for (int o = 32; o >= 1; o >>= 1) {
            s  += __shfl_xor(s, o);
            dd += __shfl_xor(dd, o);
        }
        if (lane == 0) {
            psm[wid] = (events[wid] == 1) ? s : -1e30f;
            pdv[wid] = dd;
        }
    } else if (blk < 21250) {
        int e = (blk - 20000) * 256 + tid;          // exactly covers NE
        atomicAdd(&deg[dst[e]], 1);
    } else {
        int f = (blk - 21250) * 256 + tid;          // exactly 4096
        int lane  = f & 63;
        int tile  = f >> 6;
        int kstep = tile >> 3, ntile = tile & 7;
        int k0 = kstep * 32 + (lane >> 4) * 8;
        int n  = ntile * 16 + (lane & 15);
        unsigned short h[8];
        #pragma unroll
        for (int j = 0; j < 8; ++j)
            h[j] = f2bf(W[(size_t)(k0 + j) * HH + n]);
        uint4 q;
        q.x = h[0] | ((unsigned)h[1] << 16);
        q.y = h[2] | ((unsigned)h[3] << 16);
        q.z = h[4] | ((unsigned)h[5] << 16);
        q.w = h[6] | ((unsigned)h[7] << 16);
        wp[f] = q;
    }
}

// agg over bf16 rows; split wave: lanes 0-31 even compact rows, 32-63 odd.
// each lane covers features [4*sl .. 4*sl+3]; output bf16.
__global__ __launch_bounds__(256) void aggA_kernel(
        const unsigned* __restrict__ nfb,
        const float* __restrict__ psm,
        const float* __restrict__ pdv,
        const int* __restrict__ offsets,
        const int* __restrict__ ssrc,
        unsigned* __restrict__ aggb) {
    __shared__ int2 led[TT][64];
    int t    = threadIdx.x >> 6;
    int lane = threadIdx.x & 63;
    int d    = blockIdx.x;
    int off = offsets[d], end = offsets[d + 1];
    float pd = pdv[d * TT + t];
    int half = lane >> 5, sl = lane & 31;

    float a0 = 0.f, a1 = 0.f, a2 = 0.f, a3 = 0.f;
    float den = 0.f;
    for (int base = off; base < end; base += 64) {
        int i = base + lane;
        float ex = 0.f; int s = 0;
        if (i < end) {
            s = ssrc[i];
            float p = psm[s * TT + t];
            if (p > -1e29f) {
                float x = p + pd;
                x = (x > 0.f) ? x : 0.2f * x;   // leaky_relu 0.2
                ex = __expf(x);
            }
        }
        den += ex;
        unsigned long long mask = __ballot(ex > 0.f);
        int nact = __popcll(mask);
        if (ex > 0.f) {
            int pos = __popcll(mask & ((1ull << lane) - 1ull));
            led[t][pos] = make_int2(s, __float_as_int(ex));
        }
        int j = 0;
        for (; j + 8 <= nact; j += 8) {
            #pragma unroll
            for (int u = 0; u < 4; ++u) {
                int2 a = led[t][j + 2 * u + half];
                uint2 v = *(const uint2*)&nfb[(((size_t)a.x * TT + t) << 6) + sl * 2];
                float e = __int_as_float(a.y);
                a0 += e * bf_lo(v.x); a1 += e * bf_hi(v.x);
                a2 += e * bf_lo(v.y); a3 += e * bf_hi(v.y);
            }
        }
        for (; j < nact; j += 2) {
            int idx = j + half;
            if (idx < nact) {
                int2 a = led[t][idx];
                uint2 v = *(const uint2*)&nfb[(((size_t)a.x * TT + t) << 6) + sl * 2];
                float e = __int_as_float(a.y);
                a0 += e * bf_lo(v.x); a1 += e * bf_hi(v.x);
                a2 += e * bf_lo(v.y); a3 += e * bf_hi(v.y);
            }
        }
    }
    #pragma unroll
    for (int o = 32; o >= 1; o >>= 1) den += __shfl_xor(den, o);
    // combine even/odd-row partials
    a0 += __shfl_xor(a0, 32); a1 += __shfl_xor(a1, 32);
    a2 += __shfl_xor(a2, 32); a3 += __shfl_xor(a3, 32);
    float scale = (den > 0.f) ? (1.f / den) : 0.f;
    if (half == 0) {
        uint2 o2;
        o2.x = pack2bf(a0 * scale, a1 * scale);
        o2.y = pack2bf(a2 * scale, a3 * scale);
        *(uint2*)&aggb[(((size_t)d * TT + t) << 6) + sl * 2] = o2;
    }
}

// out = relu(concat([nfb, aggb]) @ W + b) via bf16 MFMA; pure-copy staging.
__global__ __launch_bounds__(256) void outA_kernel(
        const uint4* __restrict__ nfb4, const uint4* __restrict__ wp,
        const float* __restrict__ b, const uint4* __restrict__ aggb4,
        float* __restrict__ out) {
    __shared__ uint4 xs[2048];   // 32 KB
    int tid = threadIdx.x;
    size_t row0 = (size_t)blockIdx.x * 64;

    #pragma unroll
    for (int i = 0; i < 8; ++i) {
        int c = i * 256 + tid;
        int row = c >> 5, kc = c & 31;
        size_t grow = row0 + row;
        uint4 q = (kc < 16) ? nfb4[grow * 16 + kc] : aggb4[grow * 16 + (kc - 16)];
        xs[(row * 32 + kc) ^ (row & 7)] = q;
    }
    __syncthreads();

    int w = tid >> 6, l = tid & 63;
    f32x4 acc[8];
    #pragma unroll
    for (int nt = 0; nt < 8; ++nt) acc[nt] = (f32x4){0.f, 0.f, 0.f, 0.f};

    int arow = w * 16 + (l & 15);
    const uint4* wplane = wp + l;
    #pragma unroll
    for (int ks = 0; ks < 8; ++ks) {
        int kc = ks * 4 + (l >> 4);
        uint4 av = xs[(arow * 32 + kc) ^ (arow & 7)];
        short8v af = __builtin_bit_cast(short8v, av);
        #pragma unroll
        for (int nt = 0; nt < 8; ++nt) {
            uint4 bv = wplane[(ks * 8 + nt) * 64];
            short8v bf = __builtin_bit_cast(short8v, bv);
            acc[nt] = __builtin_amdgcn_mfma_f32_16x16x32_bf16(af, bf, acc[nt], 0, 0, 0);
        }
    }

    int col = l & 15, rquad = (l >> 4) * 4;
    #pragma unroll
    for (int nt = 0; nt < 8; ++nt) {
        float bias = b[nt * 16 + col];
        #pragma unroll
        for (int r = 0; r < 4; ++r) {
            float v = acc[nt][r] + bias;
            out[(row0 + w * 16 + rquad + r) * HH + nt * 16 + col] = fmaxf(v, 0.f);
        }
    }
}

// ===========================================================================
// Tier B (small workspace): round-3 fp32 path
// ===========================================================================
__global__ void projB_kernel(const float* __restrict__ nf,
                             const int* __restrict__ events,
                             const float* __restrict__ a_src,
                             const float* __restrict__ a_dst,
                             float* __restrict__ psm, float* __restrict__ pdv,
                             int total) {
    int wid  = (blockIdx.x * blockDim.x + threadIdx.x) >> 6;
    int lane = threadIdx.x & 63;
    if (wid >= total) return;
    float2 v  = ((const float2*)nf)[(size_t)wid * 64 + lane];
    float2 as = ((const float2*)a_src)[lane];
    float2 ad = ((const float2*)a_dst)[lane];
    float s  = v.x * as.x + v.y * as.y;
    float dd = v.x * ad.x + v.y * ad.y;
    #pragma unroll
    for (int o = 32; o >= 1; o >>= 1) {
        s  += __shfl_xor(s, o);
        dd += __shfl_xor(dd, o);
    }
    if (lane == 0) {
        psm[wid] = (events[wid] == 1) ? s : -1e30f;
        pdv[wid] = dd;
    }
}

__global__ void histB_kernel(const int* __restrict__ dst, int* __restrict__ deg, int n) {
    int e = blockIdx.x * blockDim.x + threadIdx.x;
    if (e < n) atomicAdd(&deg[dst[e]], 1);
}

__global__ __launch_bounds__(256) void aggB_kernel(
        const float* __restrict__ nf,
        const float* __restrict__ psm,
        const float* __restrict__ pdv,
        const int* __restrict__ offsets,
        const int* __restrict__ ssrc,
        float* __restrict__ agg) {
    __shared__ int2 led[TT][64];
    int t    = threadIdx.x >> 6;
    int lane = threadIdx.x & 63;
    int d    = blockIdx.x;
    int off = offsets[d], end = offsets[d + 1];
    float pd = pdv[d * TT + t];
    const float2* nf2 = (const float2*)nf;
    size_t tl = (size_t)t * 64 + lane;

    float2 acc = {0.f, 0.f};
    float den = 0.f;
    for (int base = off; base < end; base += 64) {
        int i = base + lane;
        float ex = 0.f; int s = 0;
        if (i < end) {
            s = ssrc[i];
            float p = psm[s * TT + t];
            if (p > -1e29f) {
                float x = p + pd;
                x = (x > 0.f) ? x : 0.2f * x;
                ex = __expf(x);
            }
        }
        den += ex;
        unsigned long long mask = __ballot(ex > 0.f);
        int nact = __popcll(mask);
        if (ex > 0.f) {
            int pos = __popcll(mask & ((1ull << lane) - 1ull));
            led[t][pos] = make_int2(s, __float_as_int(ex));
        }
        int j = 0;
        for (; j + 4 <= nact; j += 4) {
            int2 a0 = led[t][j], a1 = led[t][j + 1], a2 = led[t][j + 2], a3 = led[t][j + 3];
            float2 r0 = nf2[(size_t)a0.x * 256 + tl];
            float2 r1 = nf2[(size_t)a1.x * 256 + tl];
            float2 r2 = nf2[(size_t)a2.x * 256 + tl];
            float2 r3 = nf2[(size_t)a3.x * 256 + tl];
            float e0 = __int_as_float(a0.y), e1 = __int_as_float(a1.y);
            float e2 = __int_as_float(a2.y), e3 = __int_as_float(a3.y);
            acc.x += e0 * r0.x; acc.y += e0 * r0.y;
            acc.x += e1 * r1.x; acc.y += e1 * r1.y;
            acc.x += e2 * r2.x; acc.y += e2 * r2.y;
            acc.x += e3 * r3.x; acc.y += e3 * r3.y;
        }
        for (; j < nact; ++j) {
            int2 a = led[t][j];
            float2 r = nf2[(size_t)a.x * 256 + tl];
            float e = __int_as_float(a.y);
            acc.x += e * r.x; acc.y += e * r.y;
        }
    }
    #pragma unroll
    for (int o = 32; o >= 1; o >>= 1) den += __shfl_xor(den, o);
    float scale = (den > 0.f) ? (1.f / den) : 0.f;
    float2 res; res.x = acc.x * scale; res.y = acc.y * scale;
    ((float2*)agg)[(size_t)d * 256 + tl] = res;
}

__global__ void wpackB_kernel(const float* __restrict__ W, uint4* __restrict__ wp) {
    int f = blockIdx.x * blockDim.x + threadIdx.x;
    if (f >= 8 * 8 * 64) return;
    int lane  = f & 63;
    int tile  = f >> 6;
    int kstep = tile >> 3, ntile = tile & 7;
    int k0 = kstep * 32 + (lane >> 4) * 8;
    int n  = ntile * 16 + (lane & 15);
    unsigned short h[8];
    #pragma unroll
    for (int j = 0; j < 8; ++j)
        h[j] = f2bf(W[(size_t)(k0 + j) * HH + n]);
    uint4 q;
    q.x = h[0] | ((unsigned)h[1] << 16);
    q.y = h[2] | ((unsigned)h[3] << 16);
    q.z = h[4] | ((unsigned)h[5] << 16);
    q.w = h[6] | ((unsigned)h[7] << 16);
    wp[f] = q;
}

__global__ __launch_bounds__(256) void outB_kernel(
        const float* __restrict__ nf, const uint4* __restrict__ wp,
        const float* __restrict__ b, float* __restrict__ out) {
    __shared__ uint4 xs[2048];
    int tid = threadIdx.x;
    size_t row0 = (size_t)blockIdx.x * 64;

    #pragma unroll
    for (int i = 0; i < 8; ++i) {
        int c = i * 256 + tid;
        int row = c >> 5, kc = c & 31;
        const float* srcp = (kc < 16) ? (nf  + (row0 + row) * HH + kc * 8)
                                      : (out + (row0 + row) * HH + (kc - 16) * 8);
        float4 v0 = *reinterpret_cast<const float4*>(srcp);
        float4 v1 = *reinterpret_cast<const float4*>(srcp + 4);
        uint4 q;
        q.x = pack2bf(v0.x, v0.y);
        q.y = pack2bf(v0.z, v0.w);
        q.z = pack2bf(v1.x, v1.y);
        q.w = pack2bf(v1.z, v1.w);
        xs[(row * 32 + kc) ^ (row & 7)] = q;
    }
    __syncthreads();

    int w = tid >> 6, l = tid & 63;
    f32x4 acc[8];
    #pragma unroll
    for (int nt = 0; nt < 8; ++nt) acc[nt] = (f32x4){0.f, 0.f, 0.f, 0.f};

    int arow = w * 16 + (l & 15);
    const uint4* wplane = wp + l;
    #pragma unroll
    for (int ks = 0; ks < 8; ++ks) {
        int kc = ks * 4 + (l >> 4);
        uint4 av = xs[(arow * 32 + kc) ^ (arow & 7)];
        short8v af = __builtin_bit_cast(short8v, av);
        #pragma unroll
        for (int nt = 0; nt < 8; ++nt) {
            uint4 bv = wplane[(ks * 8 + nt) * 64];
            short8v bf = __builtin_bit_cast(short8v, bv);
            acc[nt] = __builtin_amdgcn_mfma_f32_16x16x32_bf16(af, bf, acc[nt], 0, 0, 0);
        }
    }

    int col = l & 15, rquad = (l >> 4) * 4;
    #pragma unroll
    for (int nt = 0; nt < 8; ++nt) {
        float bias = b[nt * 16 + col];
        #pragma unroll
        for (int r = 0; r < 4; ++r) {
            float v = acc[nt][r] + bias;
            out[(row0 + w * 16 + rquad + r) * HH + nt * 16 + col] = fmaxf(v, 0.f);
        }
    }
}

// ===========================================================================
extern "C" void kernel_launch(void* const* d_in, const int* in_sizes, int n_in,
                              void* d_out, int out_size, void* d_ws, size_t ws_size,
                              hipStream_t stream) {
    const float* nf      = (const float*)d_in[0];
    const int*   events  = (const int*)  d_in[1];
    const int*   src     = (const int*)  d_in[2];
    const int*   dst     = (const int*)  d_in[3];
    const float* a_src   = (const float*)d_in[4];
    const float* a_dst   = (const float*)d_in[5];
    const float* W       = (const float*)d_in[6];
    const float* b       = (const float*)d_in[7];
    float* out = (float*)d_out;

    const int total_nt = NN * TT;   // 80000
    char* ws = (char*)d_ws;

    const size_t NEED_A = 43200000;
    if (ws_size >= NEED_A) {
        // ---- Tier A layout ----
        unsigned* nfb   = (unsigned*)(ws);                 // 20,480,000 B
        unsigned* aggb  = (unsigned*)(ws + 20480000);      // 20,480,000 B
        float* psm      = (float*)(ws + 40960000);         //    320,000 B
        float* pdv      = (float*)(ws + 41280000);         //    320,000 B
        int*   offsets  = (int*)  (ws + 41600000);         //     80,004 B
        int*   deg      = (int*)  (ws + 41680128);         //     80,000 B
        int*   cursor   = (int*)  (ws + 41760128);         //     80,004 B
        int*   ssrc     = (int*)  (ws + 41840384);         //  1,280,000 B
        uint4* wpack    = (uint4*)(ws + 43120640);         //     65,536 B

        hipMemsetAsync(deg, 0, NN * sizeof(int), stream);
        fusedA_kernel<<<21266, 256, 0, stream>>>(nf, events, a_src, a_dst, dst, W,
                                                 psm, pdv, nfb, deg, wpack);
        scan_kernel<<<1, 1024, 0, stream>>>(deg, offsets, cursor, NN);
        scatter_kernel<<<(NE + 255) / 256, 256, 0, stream>>>(src, dst, cursor, ssrc, NE);
        aggA_kernel<<<NN, 256, 0, stream>>>(nfb, psm, pdv, offsets, ssrc, aggb);
        outA_kernel<<<total_nt / 64, 256, 0, stream>>>((const uint4*)nfb, wpack, b,
                                                       (const uint4*)aggb, out);
    } else {
        // ---- Tier B layout (round-3 path) ----
        float* psm     = (float*)(ws);
        float* pdv     = (float*)(ws + 1310720);
        int*   offsets = (int*)  (ws + 2621440);
        int*   deg     = (int*)  (ws + 2703360);
        int*   cursor  = (int*)  (ws + 2785280);
        int*   ssrc    = (int*)  (ws + 2867200);
        uint4* wpack   = (uint4*)(ws);                    // aliases dead psm

        hipMemsetAsync(deg, 0, NN * sizeof(int), stream);
        projB_kernel<<<total_nt / 4, 256, 0, stream>>>(nf, events, a_src, a_dst, psm, pdv, total_nt);
        histB_kernel<<<(NE + 255) / 256, 256, 0, stream>>>(dst, deg, NE);
        scan_kernel<<<1, 1024, 0, stream>>>(deg, offsets, cursor, NN);
        scatter_kernel<<<(NE + 255) / 256, 256, 0, stream>>>(src, dst, cursor, ssrc, NE);
        aggB_kernel<<<NN, 256, 0, stream>>>(nf, psm, pdv, offsets, ssrc, out);
        wpackB_kernel<<<16, 256, 0, stream>>>(W, wpack);
        outB_kernel<<<total_nt / 64, 256, 0, stream>>>(nf, wpack, b, out);
    }
}